// Round 1
// 675.745 us; speedup vs baseline: 1.1687x; 1.1687x over previous
//
#include <hip/hip_runtime.h>
#include <math.h>

// Problem constants (match reference)
#define NB 128          // graphs in batch
#define NL 1024         // links per graph
static constexpr float P_TX    = 10.0f;
static constexpr float P_NOISE = 6.2946e-14f;
static constexpr float INV_LN2 = 1.44269504088896340736f;

// Tiling: 4 waves/block, 8 rows/wave -> 32 rows/block, 32 blocks/graph.
// py is staged once per 32 rows (was once per 4), and each wave's LDS
// read of p4 is shared across 8 H-rows (8 outstanding 16B loads/lane).
#define RPW 8                       // rows per wave
#define NWAVES 4
#define RPB (RPW * NWAVES)          // 32 rows per block
#define BLKS_PER_GRAPH (NL / RPB)   // 32

// ---------------------------------------------------------------------------
// Workspace layout: float rsum[NB]  (per-graph sum of rates)
// ---------------------------------------------------------------------------

__global__ void init_ws_kernel(float* __restrict__ rsum) {
    int t = threadIdx.x;
    if (t < NB) rsum[t] = 0.0f;
}

__global__ __launch_bounds__(256) void rows_kernel(
        const float* __restrict__ prob,   // [NB*NL, 2]
        const float* __restrict__ H,      // [NB, NL, NL]
        float* __restrict__ rsum)         // [NB]
{
    __shared__ float py[NL];        // P_TX * y for this graph
    __shared__ float rpart[NWAVES]; // per-wave partial sum of R

    const int b    = blockIdx.x / BLKS_PER_GRAPH;
    const int row0 = (blockIdx.x % BLKS_PER_GRAPH) * RPB;
    const int tid  = threadIdx.x;

    // Stage Py[b][:] into LDS (coalesced float2 loads of prob pairs).
    {
        const float2* p2 = (const float2*)prob + (size_t)b * NL;
        #pragma unroll
        for (int i = 0; i < NL / 256; ++i) {
            int j = tid + 256 * i;
            py[j] = P_TX * p2[j].y;
        }
    }
    __syncthreads();

    const int wave  = tid >> 6;
    const int lane  = tid & 63;
    const int kbase = row0 + wave * RPW;
    const float* __restrict__ Hbase = H + ((size_t)b * NL + kbase) * NL;

    float acc[RPW];
    #pragma unroll
    for (int r = 0; r < RPW; ++r) acc[r] = 0.0f;

    // total[b,k] = sum_j H[b,k,j]^2 * Py[j]
    // One LDS float4 read shared across 8 rows; 8 global float4 in flight.
    #pragma unroll
    for (int it = 0; it < 4; ++it) {
        const int j = it * 256 + lane * 4;
        const float4 p4 = *(const float4*)(&py[j]);
        #pragma unroll
        for (int r = 0; r < RPW; ++r) {
            float4 h4 = *(const float4*)(Hbase + (size_t)r * NL + j);
            acc[r] = fmaf(h4.x * h4.x, p4.x, acc[r]);
            acc[r] = fmaf(h4.y * h4.y, p4.y, acc[r]);
            acc[r] = fmaf(h4.z * h4.z, p4.z, acc[r]);
            acc[r] = fmaf(h4.w * h4.w, p4.w, acc[r]);
        }
    }

    // 64-lane wave reductions (result valid on lane 0).
    #pragma unroll
    for (int r = 0; r < RPW; ++r) {
        float a = acc[r];
        #pragma unroll
        for (int off = 32; off >= 1; off >>= 1)
            a += __shfl_down(a, off, 64);
        acc[r] = a;
    }

    if (lane == 0) {
        float s = 0.0f;
        #pragma unroll
        for (int r = 0; r < RPW; ++r) {
            const int k  = kbase + r;
            float hd     = Hbase[(size_t)r * NL + k];   // diagonal, L2-hot
            float sig    = hd * hd * py[k];
            float interf = acc[r] - sig + P_NOISE;
            s += log1pf(sig / interf) * INV_LN2;
        }
        rpart[wave] = s;
    }
    __syncthreads();

    if (tid == 0) {
        float s = rpart[0] + rpart[1] + rpart[2] + rpart[3];
        atomicAdd(&rsum[b], s);
    }
}

// loss = mean_b 1 / rsum[b]; single block of 128 threads.
__global__ void final_kernel(const float* __restrict__ rsum,
                             float* __restrict__ out)
{
    int t = threadIdx.x;             // 0..127
    float v = (1.0f / rsum[t]) * (1.0f / (float)NB);
    #pragma unroll
    for (int off = 32; off >= 1; off >>= 1)
        v += __shfl_down(v, off, 64);
    __shared__ float partial[2];
    if ((t & 63) == 0) partial[t >> 6] = v;
    __syncthreads();
    if (t == 0) out[0] = partial[0] + partial[1];
}

extern "C" void kernel_launch(void* const* d_in, const int* in_sizes, int n_in,
                              void* d_out, int out_size, void* d_ws, size_t ws_size,
                              hipStream_t stream) {
    const float* prob = (const float*)d_in[0];  // [NB*NL, 2]
    const float* H    = (const float*)d_in[1];  // [NB, NL, NL]
    float* out  = (float*)d_out;                // scalar
    float* rsum = (float*)d_ws;                 // NB floats

    init_ws_kernel<<<1, 128, 0, stream>>>(rsum);
    rows_kernel<<<NB * BLKS_PER_GRAPH, 256, 0, stream>>>(prob, H, rsum);
    final_kernel<<<1, 128, 0, stream>>>(rsum, out);
}

// Round 3
// 667.141 us; speedup vs baseline: 1.1838x; 1.0129x over previous
//
#include <hip/hip_runtime.h>
#include <math.h>

// Problem constants (match reference)
#define NB 128          // graphs in batch
#define NL 1024         // links per graph
static constexpr float P_TX    = 10.0f;
static constexpr float P_NOISE = 6.2946e-14f;
static constexpr float INV_LN2 = 1.44269504088896340736f;

// Tiling: 4 waves/block, 8 rows/wave -> 32 rows/block, 32 blocks/graph.
#define RPW 8                       // rows per wave
#define NWAVES 4
#define RPB (RPW * NWAVES)          // 32 rows per block
#define BLKS_PER_GRAPH (NL / RPB)   // 32

// Native clang vector type for __builtin_nontemporal_load
// (HIP's float4 is a class type the builtin rejects).
typedef float fvec4 __attribute__((ext_vector_type(4)));

// ---------------------------------------------------------------------------
// Workspace layout: float partial[BLKS_PER_GRAPH][NB]
//   partial[c][b] = sum of R over the 32 rows of chunk c of graph b.
// Every slot is written unconditionally -> no init kernel, no atomics,
// safe against poisoned workspace.
// ---------------------------------------------------------------------------

__global__ __launch_bounds__(256) void rows_kernel(
        const float* __restrict__ prob,   // [NB*NL, 2]
        const float* __restrict__ H,      // [NB, NL, NL]
        float* __restrict__ partial)      // [BLKS_PER_GRAPH][NB]
{
    __shared__ float py[NL];        // P_TX * y for this graph
    __shared__ float rpart[NWAVES]; // per-wave partial sum of R

    const int b    = blockIdx.x / BLKS_PER_GRAPH;
    const int c    = blockIdx.x % BLKS_PER_GRAPH;
    const int row0 = c * RPB;
    const int tid  = threadIdx.x;

    // Stage Py[b][:] into LDS (coalesced float2 loads of prob pairs).
    {
        const float2* p2 = (const float2*)prob + (size_t)b * NL;
        #pragma unroll
        for (int i = 0; i < NL / 256; ++i) {
            int j = tid + 256 * i;
            py[j] = P_TX * p2[j].y;
        }
    }
    __syncthreads();

    const int wave  = tid >> 6;
    const int lane  = tid & 63;
    const int kbase = row0 + wave * RPW;
    const float* __restrict__ Hbase = H + ((size_t)b * NL + kbase) * NL;

    float acc[RPW];
    #pragma unroll
    for (int r = 0; r < RPW; ++r) acc[r] = 0.0f;

    // total[b,k] = sum_j H[b,k,j]^2 * Py[j]
    // One LDS float4 read shared across 8 rows; 8 nontemporal 16B global
    // loads in flight per lane (H is streamed exactly once -> bypass L2/L3).
    #pragma unroll
    for (int it = 0; it < 4; ++it) {
        const int j = it * 256 + lane * 4;
        const float4 p4 = *(const float4*)(&py[j]);
        #pragma unroll
        for (int r = 0; r < RPW; ++r) {
            fvec4 h4 = __builtin_nontemporal_load(
                            (const fvec4*)(Hbase + (size_t)r * NL + j));
            acc[r] = fmaf(h4.x * h4.x, p4.x, acc[r]);
            acc[r] = fmaf(h4.y * h4.y, p4.y, acc[r]);
            acc[r] = fmaf(h4.z * h4.z, p4.z, acc[r]);
            acc[r] = fmaf(h4.w * h4.w, p4.w, acc[r]);
        }
    }

    // 64-lane wave reductions (result valid on lane 0).
    #pragma unroll
    for (int r = 0; r < RPW; ++r) {
        float a = acc[r];
        #pragma unroll
        for (int off = 32; off >= 1; off >>= 1)
            a += __shfl_down(a, off, 64);
        acc[r] = a;
    }

    if (lane == 0) {
        float s = 0.0f;
        #pragma unroll
        for (int r = 0; r < RPW; ++r) {
            const int k  = kbase + r;
            float hd     = Hbase[(size_t)r * NL + k];   // diagonal, cache-hot
            float sig    = hd * hd * py[k];
            float interf = acc[r] - sig + P_NOISE;
            s += log1pf(sig / interf) * INV_LN2;
        }
        rpart[wave] = s;
    }
    __syncthreads();

    if (tid == 0) {
        // partial[c][b]: coalesced across b for the final reduction.
        partial[(size_t)c * NB + b] =
            rpart[0] + rpart[1] + rpart[2] + rpart[3];
    }
}

// loss = mean_b 1 / sum_c partial[c][b]; single block of 128 threads.
__global__ void final_kernel(const float* __restrict__ partial,
                             float* __restrict__ out)
{
    int b = threadIdx.x;             // 0..127 = graph index
    float rsum = 0.0f;
    #pragma unroll
    for (int c = 0; c < BLKS_PER_GRAPH; ++c)
        rsum += partial[(size_t)c * NB + b];   // coalesced across lanes

    float v = (1.0f / rsum) * (1.0f / (float)NB);
    #pragma unroll
    for (int off = 32; off >= 1; off >>= 1)
        v += __shfl_down(v, off, 64);
    __shared__ float ps[2];
    if ((b & 63) == 0) ps[b >> 6] = v;
    __syncthreads();
    if (b == 0) out[0] = ps[0] + ps[1];
}

extern "C" void kernel_launch(void* const* d_in, const int* in_sizes, int n_in,
                              void* d_out, int out_size, void* d_ws, size_t ws_size,
                              hipStream_t stream) {
    const float* prob    = (const float*)d_in[0];  // [NB*NL, 2]
    const float* H       = (const float*)d_in[1];  // [NB, NL, NL]
    float* out     = (float*)d_out;                // scalar
    float* partial = (float*)d_ws;                 // BLKS_PER_GRAPH*NB floats

    rows_kernel<<<NB * BLKS_PER_GRAPH, 256, 0, stream>>>(prob, H, partial);
    final_kernel<<<1, 128, 0, stream>>>(partial, out);
}